// Round 10
// baseline (383.778 us; speedup 1.0000x reference)
//
#include <hip/hip_runtime.h>
#include <hip/hip_bf16.h>
#include <math.h>

#define B 8
#define C 64
#define NN 4096
#define O 64
#define KNN 20

typedef float f32x4 __attribute__((ext_vector_type(4)));
typedef short short8_t __attribute__((ext_vector_type(8)));

__device__ inline uint32_t fkey(float f) {
    uint32_t u = __float_as_uint(f);
    return u ^ (((uint32_t)((int32_t)u >> 31)) | 0x80000000u);
}

__device__ inline uint32_t med3u(uint32_t a, uint32_t b, uint32_t c) {
    uint32_t r;
    asm("v_med3_u32 %0, %1, %2, %3" : "=v"(r) : "v"(a), "v"(b), "v"(c));
    return r;
}
__device__ inline uint32_t umax(uint32_t a, uint32_t b) { return a > b ? a : b; }
__device__ inline uint32_t umin(uint32_t a, uint32_t b) { return a < b ? a : b; }

// reduce over each 16-lane group, result in ALL 16 lanes. Pure VALU (DPP).
__device__ inline uint32_t maxall16(uint32_t v) {
    uint32_t t;
    t = (uint32_t)__builtin_amdgcn_update_dpp(0, (int)v, 0x140, 0xF, 0xF, true); // row_mirror
    v = umax(v, t);
    t = (uint32_t)__builtin_amdgcn_update_dpp(0, (int)v, 0x141, 0xF, 0xF, true); // row_half_mirror
    v = umax(v, t);
    t = (uint32_t)__builtin_amdgcn_update_dpp(0, (int)v, 0x4E, 0xF, 0xF, true);  // quad_perm [2,3,0,1]
    v = umax(v, t);
    t = (uint32_t)__builtin_amdgcn_update_dpp(0, (int)v, 0xB1, 0xF, 0xF, true);  // quad_perm [1,0,3,2]
    v = umax(v, t);
    return v;
}
__device__ inline uint32_t minall16(uint32_t v) {
    uint32_t t;
    t = (uint32_t)__builtin_amdgcn_update_dpp(0, (int)v, 0x140, 0xF, 0xF, true);
    v = umin(v, t);
    t = (uint32_t)__builtin_amdgcn_update_dpp(0, (int)v, 0x141, 0xF, 0xF, true);
    v = umin(v, t);
    t = (uint32_t)__builtin_amdgcn_update_dpp(0, (int)v, 0x4E, 0xF, 0xF, true);
    v = umin(v, t);
    t = (uint32_t)__builtin_amdgcn_update_dpp(0, (int)v, 0xB1, 0xF, 0xF, true);
    v = umin(v, t);
    return v;
}

// ---------------- K1: x (B,C,N) -> xt f32 (B,N,C) + xh bf16 (B,N,C), xx = sum_c x^2 ----------------
__global__ __launch_bounds__(256) void k1_split(const float* __restrict__ x,
                                                float* __restrict__ xt,
                                                __hip_bfloat16* __restrict__ xh,
                                                float* __restrict__ xx) {
    __shared__ float tile[64][65];
    int b  = blockIdx.x / (NN / 64);
    int n0 = (blockIdx.x % (NN / 64)) * 64;
    int t = threadIdx.x;
    #pragma unroll
    for (int it = 0; it < 16; ++it) {
        int i = it * 256 + t;
        int c = i >> 6, n = i & 63;
        tile[c][n] = x[(size_t)b * C * NN + (size_t)c * NN + n0 + n];
    }
    __syncthreads();
    #pragma unroll
    for (int it = 0; it < 16; ++it) {
        int i = it * 256 + t;
        int n = i >> 6, c = i & 63;
        float v = tile[c][n];
        size_t off = ((size_t)(b * NN + n0 + n)) * C + c;
        xt[off] = v;
        xh[off] = __float2bfloat16(v);
    }
    if (t < 64) {
        float s = 0.f;
        #pragma unroll
        for (int c = 0; c < 64; ++c) { float v = tile[c][t]; s = fmaf(v, v, s); }
        xx[(size_t)b * NN + t + n0] = s;
    }
}

// ---------------- K2: bf16-MFMA approx filter -> per-wave top-20 (pool 80) -> exact f32 top-20 ----------------
// XCD swizzle: b = blockIdx&7 pins each batch's xh/xt/xx to one XCD's L2.
// Sweep: min-convention keys — d' = 2a - xxc - xxq - 2 is ALWAYS negative, so raw
// as_uint orders inversely; packed (key20|col12), min-queue depth 10 via med3.
// Waves partition candidates; per-wave DPP tournament extracts top-20 (a strip can
// hold at most 20 of the true top-20 -> no count truncation, only noise demotion
// with >=21-r_s interlopers — tail-negligible; this is the R8-validated slack).
// Pool 4x20 = 80, NO cross-wave merge, NO approx trim: exact f32 rerank of ALL 80
// (strictly safer than the passing R8, which trimmed 80->32 by approx key).
// Final: 20-round DPP max-tournament on exact fkeys, ballot-deterministic winner.
__global__ __launch_bounds__(256) void k2_knn(const __hip_bfloat16* __restrict__ xh,
                                              const float* __restrict__ xt,
                                              const float* __restrict__ xx,
                                              int* __restrict__ idx) {
    int b  = blockIdx.x & 7;
    int n0 = (blockIdx.x >> 3) << 4;
    int t = threadIdx.x;
    int w = t >> 6, lane = t & 63;
    int laneid = lane & 15, grp = lane >> 4;

    const __hip_bfloat16* xhb = xh + (size_t)b * NN * 64;
    const float* xxb = xx + (size_t)b * NN;
    const float* xtb = xt + (size_t)b * NN * 64;

    // A fragments: row = query n0+laneid, k = grp*8 .. grp*8+7 (and +32)
    size_t qoff = (size_t)(n0 + laneid) * 64 + grp * 8;
    short8_t Ah0 = *(const short8_t*)(xhb + qoff);
    short8_t Ah1 = *(const short8_t*)(xhb + qoff + 32);

    // per-query bias: -xxq - 2  (group's queries are n0+grp*4+j)
    float bq[4];
    #pragma unroll
    for (int j = 0; j < 4; ++j) bq[j] = -2.f - xxb[n0 + grp * 4 + j];

    // per-lane sorted min-queues (ascending), packed u32 entries
    uint32_t qq[4][10];
    #pragma unroll
    for (int j = 0; j < 4; ++j)
        #pragma unroll
        for (int i = 0; i < 10; ++i) qq[j][i] = 0xFFFFFFFFu;

    // ---- sweep: 64 tiles with prefetch ----
    int cand0 = w * 1024 + laneid;
    {
        const __hip_bfloat16* p0 = xhb + (size_t)cand0 * 64 + grp * 8;
        short8_t nB0 = *(const short8_t*)p0;
        short8_t nB1 = *(const short8_t*)(p0 + 32);
        float nxx = xxb[cand0];
        #pragma unroll 4
        for (int tt = 0; tt < 64; ++tt) {
            short8_t B0 = nB0, B1 = nB1;
            float xxc = nxx;
            int ci = cand0 + tt * 16;
            // prefetch next tile (tt==63 over-reads <=2KB into adjacent workspace
            // arrays — allocated, values unused)
            {
                const __hip_bfloat16* np = xhb + (size_t)(ci + 16) * 64 + grp * 8;
                nB0 = *(const short8_t*)np;
                nB1 = *(const short8_t*)(np + 32);
                nxx = xxb[ci + 16];
            }
            f32x4 acc = {0.f, 0.f, 0.f, 0.f};
            acc = __builtin_amdgcn_mfma_f32_16x16x32_bf16(Ah0, B0, acc, 0, 0, 0);
            acc = __builtin_amdgcn_mfma_f32_16x16x32_bf16(Ah1, B1, acc, 0, 0, 0);
            #pragma unroll
            for (int j = 0; j < 4; ++j) {
                // d' = 2*acc - xxc - xxq - 2 < 0 always -> raw uint orders inversely
                uint32_t u = __float_as_uint(fmaf(acc[j], 2.f, bq[j] - xxc));
                uint32_t nv = (u & 0xFFFFF000u) | (uint32_t)ci;  // min -> lower col tie-break
                #pragma unroll
                for (int i = 9; i >= 1; --i)
                    qq[j][i] = med3u(qq[j][i - 1], qq[j][i], nv);
                qq[j][0] = umin(qq[j][0], nv);
            }
        }
    }

    __shared__ uint32_t cand[16][84];   // pool: [query][wave*20+round], padded
    __shared__ float qrow[16][68];      // f32 query rows, padded

    // stage f32 query rows (loads overlap extraction)
    #pragma unroll
    for (int i = 0; i < 4; ++i) {
        int e = i * 256 + t;
        int r = e >> 6, cc = e & 63;
        qrow[r][cc] = xtb[(size_t)(n0 + r) * 64 + cc];
    }

    // ---- per-wave top-20 extraction: DPP min-tournament over 16 queue heads ----
    #pragma unroll 1
    for (int r = 0; r < 20; ++r) {
        #pragma unroll
        for (int j = 0; j < 4; ++j) {
            uint32_t bk = minall16(qq[j][0]);
            bool win = (qq[j][0] == bk);   // packed values unique -> single winner
            #pragma unroll
            for (int i = 0; i < 9; ++i) qq[j][i] = win ? qq[j][i + 1] : qq[j][i];
            qq[j][9] = win ? 0xFFFFFFFFu : qq[j][9];
            if (laneid == 0) cand[grp * 4 + j][w * 20 + r] = bk & 4095u;
        }
    }
    __syncthreads();

    // ---- exact f32 rerank of 80-pool (Round-1 arithmetic), 5 entries/thread ----
    int rq = t >> 4, rs = t & 15;
    float qxx = xxb[n0 + rq];
    const float4* qr = (const float4*)qrow[rq];
    uint32_t ky[5], cl[5];
    #pragma unroll
    for (int e = 0; e < 5; ++e) {
        uint32_t col = cand[rq][rs + 16 * e];
        const float4* cr = (const float4*)(xtb + (size_t)col * 64);
        float a = 0.f;
        #pragma unroll
        for (int i = 0; i < 16; ++i) {
            float4 qv = qr[i], cv = cr[i];
            a = fmaf(qv.x, cv.x, a); a = fmaf(qv.y, cv.y, a);
            a = fmaf(qv.z, cv.z, a); a = fmaf(qv.w, cv.w, a);
        }
        float d = 2.f * a - qxx - xxb[col];
        ky[e] = fkey(d);
        cl[e] = col;
    }

    // ---- final: 20-round DPP max-tournament on exact keys, ballot-deterministic winner ----
    size_t ob = ((size_t)(b * NN) + n0 + rq) * KNN;
    int rowsh = lane & 48;   // row base within wave for ballot extraction
    #pragma unroll 1
    for (int r = 0; r < KNN; ++r) {
        uint32_t bl = umax(umax(umax(ky[0], ky[1]), umax(ky[2], ky[3])), ky[4]);
        uint32_t bg = maxall16(bl);
        bool m0 = (ky[0] == bg), m1 = (ky[1] == bg), m2 = (ky[2] == bg),
             m3 = (ky[3] == bg), m4 = (ky[4] == bg);
        bool any = m0 | m1 | m2 | m3 | m4;
        unsigned long long bal = __ballot(any);
        uint32_t rowbits = (uint32_t)((bal >> rowsh) & 0xFFFFull);
        int firstl = __builtin_ctz(rowbits);   // rowbits nonzero: bg came from this row
        if (laneid == firstl) {
            // lowest matching entry only: emit + clear exactly one
            bool c0 = m0;
            bool c1 = m1 && !m0;
            bool c2 = m2 && !(m0 | m1);
            bool c3 = m3 && !(m0 | m1 | m2);
            bool c4 = m4 && !(m0 | m1 | m2 | m3);
            uint32_t c = c0 ? cl[0] : (c1 ? cl[1] : (c2 ? cl[2] : (c3 ? cl[3] : cl[4])));
            idx[ob + r] = (int)c;
            ky[0] = c0 ? 0u : ky[0];
            ky[1] = c1 ? 0u : ky[1];
            ky[2] = c2 ? 0u : ky[2];
            ky[3] = c3 ? 0u : ky[3];
            ky[4] = c4 ? 0u : ky[4];
        }
    }
}

// ---------------- K3a: Z = xt @ W0^T, Z2 = xt @ (W1-W0)^T ----------------
__global__ __launch_bounds__(256) void k3a_gemm(const float* __restrict__ xt,
                                                const float* __restrict__ W,
                                                float* __restrict__ Z,
                                                float* __restrict__ Z2) {
    __shared__ float W0t[64][65];
    __shared__ float W21t[64][65];
    __shared__ float xs[16][64];
    int t = threadIdx.x;
    #pragma unroll
    for (int it = 0; it < 16; ++it) {
        int i = it * 256 + t;
        int o = i >> 6, c = i & 63;
        float w0 = W[o * 128 + c];
        float w1 = W[o * 128 + 64 + c];
        W0t[c][o]  = w0;
        W21t[c][o] = w1 - w0;
    }
    int b  = blockIdx.x / (NN / 16);
    int nb = (blockIdx.x % (NN / 16)) * 16;
    #pragma unroll
    for (int it = 0; it < 4; ++it) {
        int i = it * 256 + t;
        int r = i >> 6, c = i & 63;
        xs[r][c] = xt[((size_t)(b * NN + nb + r)) * C + c];
    }
    __syncthreads();
    int o = t & 63, rg = t >> 6;
    #pragma unroll
    for (int rr = 0; rr < 4; ++rr) {
        int r = rg * 4 + rr;
        float z = 0.f, z2 = 0.f;
        #pragma unroll
        for (int c = 0; c < 64; ++c) {
            float xv = xs[r][c];
            z  = fmaf(xv, W0t[c][o],  z);
            z2 = fmaf(xv, W21t[c][o], z2);
        }
        size_t off = ((size_t)(b * NN + nb + r)) * 64 + o;
        Z[off]  = z;
        Z2[off] = z2;
    }
}

// ---------------- K3b: gather neighbors, per-(b,n,o) max/min over k, block-partial sums ----------------
// XCD swizzle: b = blockIdx&7 pins each batch's Z/Z2 (2MB) to one XCD's L2.
__global__ __launch_bounds__(256) void k3b_gather(const float* __restrict__ Z,
                                                  const float* __restrict__ Z2,
                                                  const int* __restrict__ idx,
                                                  float* __restrict__ maxY,
                                                  float* __restrict__ minY,
                                                  float* __restrict__ partials) {
    int t = threadIdx.x;
    int p = t >> 6, o = t & 63;
    int b = blockIdx.x & 7;
    int n = (blockIdx.x >> 3) * 4 + p;
    size_t base = (size_t)(b * NN + n);
    float z2 = Z2[base * 64 + o];
    __shared__ int sidx[4][KNN];
    if (o < KNN) sidx[p][o] = idx[base * KNN + o];
    __syncthreads();
    const float* Zb = Z + (size_t)b * NN * 64;
    float s1 = 0.f, s2 = 0.f, mx = -INFINITY, mn = INFINITY;
    #pragma unroll
    for (int k = 0; k < KNN; ++k) {
        float y = Zb[(size_t)sidx[p][k] * 64 + o] + z2;
        s1 += y;
        s2 = fmaf(y, y, s2);
        mx = fmaxf(mx, y);
        mn = fminf(mn, y);
    }
    maxY[base * 64 + o] = mx;
    minY[base * 64 + o] = mn;
    __shared__ float red[2][4][64];
    red[0][p][o] = s1;
    red[1][p][o] = s2;
    __syncthreads();
    if (t < 64) {
        float a = red[0][0][t] + red[0][1][t] + red[0][2][t] + red[0][3][t];
        float c = red[1][0][t] + red[1][1][t] + red[1][2][t] + red[1][3][t];
        partials[(size_t)blockIdx.x * 128 + t]      = a;
        partials[(size_t)blockIdx.x * 128 + 64 + t] = c;
    }
}

// ---------------- K4a: reduce 8192 partial rows -> 64 rows ----------------
__global__ __launch_bounds__(256) void k4a_reduce(const float* __restrict__ partials,
                                                  float* __restrict__ partials2) {
    int g = blockIdx.x;          // 0..63
    int t = threadIdx.x;
    int col = t & 127, half = t >> 7;
    float s = 0.f;
    for (int r = half; r < 128; r += 2)
        s += partials[((size_t)g * 128 + r) * 128 + col];
    __shared__ float red[2][128];
    red[half][col] = s;
    __syncthreads();
    if (t < 128) partials2[(size_t)g * 128 + t] = red[0][t] + red[1][t];
}

// ---------------- K4b: final stats -> scale/shift per channel ----------------
__global__ __launch_bounds__(128) void k4b_stats(const float* __restrict__ partials2,
                                                 const float* __restrict__ gamma,
                                                 const float* __restrict__ beta,
                                                 float* __restrict__ ss) {
    int t = threadIdx.x;   // 0..127
    double s = 0.0;
    for (int i = 0; i < 64; ++i)
        s += (double)partials2[(size_t)i * 128 + t];
    __shared__ double red[128];
    red[t] = s;
    __syncthreads();
    if (t < 64) {
        double a = red[t], c = red[64 + t];
        double M = (double)B * NN * KNN;
        double mean = a / M;
        double var  = c / M - mean * mean;
        float sc = gamma[t] * rsqrtf((float)var + 1e-5f);
        float sh = beta[t] - (float)mean * sc;
        ss[t]      = sc;
        ss[64 + t] = sh;
    }
}

// ---------------- K5: normalize + leakyrelu + transpose to (B,O,N) ----------------
__global__ __launch_bounds__(256) void k5_out(const float* __restrict__ maxY,
                                              const float* __restrict__ minY,
                                              const float* __restrict__ ss,
                                              float* __restrict__ out) {
    __shared__ float tile[64][65];
    __shared__ float sc[64], sh[64];
    int t = threadIdx.x;
    if (t < 64) { sc[t] = ss[t]; sh[t] = ss[64 + t]; }
    int b  = blockIdx.x / (NN / 64);
    int n0 = (blockIdx.x % (NN / 64)) * 64;
    __syncthreads();
    #pragma unroll
    for (int it = 0; it < 16; ++it) {
        int i = it * 256 + t;
        int nl = i >> 6, o = i & 63;
        size_t off = ((size_t)(b * NN + n0 + nl)) * 64 + o;
        float s = sc[o];
        float v = (s >= 0.f) ? maxY[off] : minY[off];
        v = fmaf(v, s, sh[o]);
        v = (v >= 0.f) ? v : 0.2f * v;
        tile[nl][o] = v;
    }
    __syncthreads();
    #pragma unroll
    for (int it = 0; it < 16; ++it) {
        int i = it * 256 + t;
        int o = i >> 6, nl = i & 63;
        out[((size_t)(b * O + o)) * NN + n0 + nl] = tile[nl][o];
    }
}

extern "C" void kernel_launch(void* const* d_in, const int* in_sizes, int n_in,
                              void* d_out, int out_size, void* d_ws, size_t ws_size,
                              hipStream_t stream) {
    const float* x     = (const float*)d_in[0];
    const float* W     = (const float*)d_in[1];
    const float* gamma = (const float*)d_in[2];
    const float* beta  = (const float*)d_in[3];
    float* out = (float*)d_out;

    float* ws = (float*)d_ws;
    float* xx = ws;                                                // B*N
    float* xt = xx + (size_t)B * NN;                               // B*N*C f32
    __hip_bfloat16* xh = (__hip_bfloat16*)(xt + (size_t)B * NN * C); // B*N*C bf16
    int*   idx = (int*)(xh + (size_t)B * NN * C);                  // B*N*KNN ints
    float* Z   = (float*)(idx + (size_t)B * NN * KNN);             // B*N*O
    float* Z2  = Z + (size_t)B * NN * O;
    float* maxY = Z2 + (size_t)B * NN * O;
    float* minY = maxY + (size_t)B * NN * O;
    float* partials  = minY + (size_t)B * NN * O;                  // (B*N/4)*128
    float* partials2 = partials + (size_t)(B * NN / 4) * 128;      // 64*128
    float* ss = partials2 + 64 * 128;                              // 128

    k1_split<<<B * (NN / 64), 256, 0, stream>>>(x, xt, xh, xx);
    k2_knn<<<B * (NN / 16), 256, 0, stream>>>(xh, xt, xx, idx);
    k3a_gemm<<<B * (NN / 16), 256, 0, stream>>>(xt, W, Z, Z2);
    k3b_gather<<<B * (NN / 4), 256, 0, stream>>>(Z, Z2, idx, maxY, minY, partials);
    k4a_reduce<<<64, 256, 0, stream>>>(partials, partials2);
    k4b_stats<<<1, 128, 0, stream>>>(partials2, gamma, beta, ss);
    k5_out<<<B * (NN / 64), 256, 0, stream>>>(maxY, minY, ss, out);
}

// Round 11
// 256.156 us; speedup vs baseline: 1.4982x; 1.4982x over previous
//
#include <hip/hip_runtime.h>
#include <hip/hip_bf16.h>
#include <math.h>

#define B 8
#define C 64
#define NN 4096
#define O 64
#define KNN 20

typedef float f32x4 __attribute__((ext_vector_type(4)));
typedef short short8_t __attribute__((ext_vector_type(8)));

__device__ inline uint32_t fkey(float f) {
    uint32_t u = __float_as_uint(f);
    return u ^ (((uint32_t)((int32_t)u >> 31)) | 0x80000000u);
}

__device__ inline uint32_t med3u(uint32_t a, uint32_t b, uint32_t c) {
    uint32_t r;
    asm("v_med3_u32 %0, %1, %2, %3" : "=v"(r) : "v"(a), "v"(b), "v"(c));
    return r;
}
__device__ inline uint32_t umax(uint32_t a, uint32_t b) { return a > b ? a : b; }
__device__ inline uint32_t umin(uint32_t a, uint32_t b) { return a < b ? a : b; }

// reduce over each 16-lane group, result in ALL 16 lanes. Pure VALU (DPP).
__device__ inline uint32_t maxall16(uint32_t v) {
    uint32_t t;
    t = (uint32_t)__builtin_amdgcn_update_dpp(0, (int)v, 0x140, 0xF, 0xF, true); // row_mirror
    v = umax(v, t);
    t = (uint32_t)__builtin_amdgcn_update_dpp(0, (int)v, 0x141, 0xF, 0xF, true); // row_half_mirror
    v = umax(v, t);
    t = (uint32_t)__builtin_amdgcn_update_dpp(0, (int)v, 0x4E, 0xF, 0xF, true);  // quad_perm [2,3,0,1]
    v = umax(v, t);
    t = (uint32_t)__builtin_amdgcn_update_dpp(0, (int)v, 0xB1, 0xF, 0xF, true);  // quad_perm [1,0,3,2]
    v = umax(v, t);
    return v;
}
__device__ inline uint32_t minall16(uint32_t v) {
    uint32_t t;
    t = (uint32_t)__builtin_amdgcn_update_dpp(0, (int)v, 0x140, 0xF, 0xF, true);
    v = umin(v, t);
    t = (uint32_t)__builtin_amdgcn_update_dpp(0, (int)v, 0x141, 0xF, 0xF, true);
    v = umin(v, t);
    t = (uint32_t)__builtin_amdgcn_update_dpp(0, (int)v, 0x4E, 0xF, 0xF, true);
    v = umin(v, t);
    t = (uint32_t)__builtin_amdgcn_update_dpp(0, (int)v, 0xB1, 0xF, 0xF, true);
    v = umin(v, t);
    return v;
}

// ---------------- K1: x (B,C,N) -> xt f32 (B,N,C) + xh bf16 (B,N,C), xx = sum_c x^2 ----------------
__global__ __launch_bounds__(256) void k1_split(const float* __restrict__ x,
                                                float* __restrict__ xt,
                                                __hip_bfloat16* __restrict__ xh,
                                                float* __restrict__ xx) {
    __shared__ float tile[64][65];
    int b  = blockIdx.x / (NN / 64);
    int n0 = (blockIdx.x % (NN / 64)) * 64;
    int t = threadIdx.x;
    #pragma unroll
    for (int it = 0; it < 16; ++it) {
        int i = it * 256 + t;
        int c = i >> 6, n = i & 63;
        tile[c][n] = x[(size_t)b * C * NN + (size_t)c * NN + n0 + n];
    }
    __syncthreads();
    #pragma unroll
    for (int it = 0; it < 16; ++it) {
        int i = it * 256 + t;
        int n = i >> 6, c = i & 63;
        float v = tile[c][n];
        size_t off = ((size_t)(b * NN + n0 + n)) * C + c;
        xt[off] = v;
        xh[off] = __float2bfloat16(v);
    }
    if (t < 64) {
        float s = 0.f;
        #pragma unroll
        for (int c = 0; c < 64; ++c) { float v = tile[c][t]; s = fmaf(v, v, s); }
        xx[(size_t)b * NN + t + n0] = s;
    }
}

// ---------------- K2: R8 structure + min-keys + padded LDS ----------------
// XCD swizzle: b = blockIdx&7 pins each batch's xh/xt/xx to one XCD's L2.
// Sweep: min-convention keys (d' = 2a - xxc - xxq - 2 < 0 -> raw as_uint orders
// inversely, 3 ops/key), per-lane depth-12 min-queues via med3.
// Per-wave top-20 DPP min-tournament -> mbuf; merge 80->32 by approx key;
// exact f32 rerank of 32 (Round-1 arithmetic); rank loop scatter.
// LDS arrays padded to odd strides: R8's 4.29M bank conflicts were rkk/cand
// (stride 32 -> the wave's 4 rq rows alias one bank, 4-way) and qrow (stride 64).
__global__ __launch_bounds__(256) void k2_knn(const __hip_bfloat16* __restrict__ xh,
                                              const float* __restrict__ xt,
                                              const float* __restrict__ xx,
                                              int* __restrict__ idx) {
    int b  = blockIdx.x & 7;
    int n0 = (blockIdx.x >> 3) << 4;
    int t = threadIdx.x;
    int w = t >> 6, lane = t & 63;
    int laneid = lane & 15, grp = lane >> 4;

    const __hip_bfloat16* xhb = xh + (size_t)b * NN * 64;
    const float* xxb = xx + (size_t)b * NN;
    const float* xtb = xt + (size_t)b * NN * 64;

    // A fragments: row = query n0+laneid, k = grp*8 .. grp*8+7 (and +32)
    size_t qoff = (size_t)(n0 + laneid) * 64 + grp * 8;
    short8_t Ah0 = *(const short8_t*)(xhb + qoff);
    short8_t Ah1 = *(const short8_t*)(xhb + qoff + 32);

    // per-query bias: -xxq - 2  (group's queries are n0+grp*4+j)
    float bq[4];
    #pragma unroll
    for (int j = 0; j < 4; ++j) bq[j] = -2.f - xxb[n0 + grp * 4 + j];

    // per-lane sorted min-queues (ascending), packed (key20|col12)
    uint32_t qq[4][12];
    #pragma unroll
    for (int j = 0; j < 4; ++j)
        #pragma unroll
        for (int i = 0; i < 12; ++i) qq[j][i] = 0xFFFFFFFFu;

    // ---- sweep: 64 tiles with prefetch ----
    int cand0 = w * 1024 + laneid;
    {
        const __hip_bfloat16* p0 = xhb + (size_t)cand0 * 64 + grp * 8;
        short8_t nB0 = *(const short8_t*)p0;
        short8_t nB1 = *(const short8_t*)(p0 + 32);
        float nxx = xxb[cand0];
        #pragma unroll 4
        for (int tt = 0; tt < 64; ++tt) {
            short8_t B0 = nB0, B1 = nB1;
            float xxc = nxx;
            int ci = cand0 + tt * 16;
            // prefetch next tile (tt==63 over-reads <=2KB into adjacent workspace
            // arrays — allocated, values unused)
            {
                const __hip_bfloat16* np = xhb + (size_t)(ci + 16) * 64 + grp * 8;
                nB0 = *(const short8_t*)np;
                nB1 = *(const short8_t*)(np + 32);
                nxx = xxb[ci + 16];
            }
            f32x4 acc = {0.f, 0.f, 0.f, 0.f};
            acc = __builtin_amdgcn_mfma_f32_16x16x32_bf16(Ah0, B0, acc, 0, 0, 0);
            acc = __builtin_amdgcn_mfma_f32_16x16x32_bf16(Ah1, B1, acc, 0, 0, 0);
            #pragma unroll
            for (int j = 0; j < 4; ++j) {
                // d' = 2*acc - xxc - xxq - 2 < 0 always -> raw uint orders inversely
                uint32_t u = __float_as_uint(fmaf(acc[j], 2.f, bq[j] - xxc));
                uint32_t nv = (u & 0xFFFFF000u) | (uint32_t)ci;  // min -> lower col wins ties
                // ascending sorted insert: all slots read OLD values -> independent med3
                #pragma unroll
                for (int i = 11; i >= 1; --i)
                    qq[j][i] = med3u(qq[j][i - 1], qq[j][i], nv);
                qq[j][0] = umin(qq[j][0], nv);
            }
        }
    }

    __shared__ uint32_t mbuf[16][4][20];   // [query][wave][slot] = packed
    __shared__ uint32_t cand[16][33];      // approx top-32 cols per query (padded)
    __shared__ uint32_t rkk[16][33];       // exact f32 keys (padded)
    __shared__ float qrow[16][68];         // f32 query rows (padded)

    // stage f32 query rows (loads overlap extraction)
    #pragma unroll
    for (int i = 0; i < 4; ++i) {
        int e = i * 256 + t;
        int r = e >> 6, cc = e & 63;
        qrow[r][cc] = xtb[(size_t)(n0 + r) * 64 + cc];
    }

    // ---- per-wave top-20 extraction: DPP min-tournament over 16 queue heads ----
    #pragma unroll 1
    for (int r = 0; r < 20; ++r) {
        #pragma unroll
        for (int j = 0; j < 4; ++j) {
            uint32_t bk = minall16(qq[j][0]);
            bool win = (qq[j][0] == bk);   // packed values unique -> single winner
            #pragma unroll
            for (int i = 0; i < 11; ++i) qq[j][i] = win ? qq[j][i + 1] : qq[j][i];
            qq[j][11] = win ? 0xFFFFFFFFu : qq[j][11];
            if (laneid == 0) mbuf[grp * 4 + j][w][r] = bk;
        }
    }
    __syncthreads();

    // ---- merge 80 -> approx top-32 per query (min-convention) ----
    {
        int q = w * 4 + grp;
        const uint32_t* mb = &mbuf[q][0][0];
        uint32_t e0 = mb[laneid],      e1 = mb[16 + laneid], e2 = mb[32 + laneid],
                 e3 = mb[48 + laneid], e4 = mb[64 + laneid];
        #pragma unroll 1
        for (int r = 0; r < 32; ++r) {
            uint32_t bk = umin(umin(umin(e0, e1), umin(e2, e3)), e4);
            bk = minall16(bk);
            e0 = (e0 == bk) ? 0xFFFFFFFFu : e0;
            e1 = (e1 == bk) ? 0xFFFFFFFFu : e1;
            e2 = (e2 == bk) ? 0xFFFFFFFFu : e2;
            e3 = (e3 == bk) ? 0xFFFFFFFFu : e3;
            e4 = (e4 == bk) ? 0xFFFFFFFFu : e4;
            if (laneid == 0) cand[q][r] = bk & 4095u;
        }
    }
    __syncthreads();

    // ---- exact f32 rerank of 32 candidates per query (Round-1 arithmetic) ----
    int rq = t >> 4, rs = t & 15;
    float qxx = xxb[n0 + rq];
    const float4* qr = (const float4*)qrow[rq];
    uint32_t mycol[2], mykey[2];
    #pragma unroll
    for (int e = 0; e < 2; ++e) {
        uint32_t col = cand[rq][rs + 16 * e];
        const float4* cr = (const float4*)(xtb + (size_t)col * 64);
        float a = 0.f;
        #pragma unroll
        for (int i = 0; i < 16; ++i) {
            float4 qv = qr[i], cv = cr[i];
            a = fmaf(qv.x, cv.x, a); a = fmaf(qv.y, cv.y, a);
            a = fmaf(qv.z, cv.z, a); a = fmaf(qv.w, cv.w, a);
        }
        float d = 2.f * a - qxx - xxb[col];
        mycol[e] = col;
        mykey[e] = fkey(d);
        rkk[rq][rs + 16 * e] = mykey[e];
    }
    __syncthreads();
    size_t ob = ((size_t)(b * NN) + n0 + rq) * KNN;
    #pragma unroll
    for (int e = 0; e < 2; ++e) {
        uint32_t ke = mykey[e], ce = mycol[e];
        int rank = 0;
        #pragma unroll
        for (int jj = 0; jj < 32; ++jj) {
            uint32_t kj = rkk[rq][jj], cj = cand[rq][jj];
            rank += (kj > ke || (kj == ke && cj < ce)) ? 1 : 0;
        }
        if (rank < KNN) idx[ob + rank] = (int)ce;
    }
}

// ---------------- K3a: Z = xt @ W0^T, Z2 = xt @ (W1-W0)^T ----------------
__global__ __launch_bounds__(256) void k3a_gemm(const float* __restrict__ xt,
                                                const float* __restrict__ W,
                                                float* __restrict__ Z,
                                                float* __restrict__ Z2) {
    __shared__ float W0t[64][65];
    __shared__ float W21t[64][65];
    __shared__ float xs[16][64];
    int t = threadIdx.x;
    #pragma unroll
    for (int it = 0; it < 16; ++it) {
        int i = it * 256 + t;
        int o = i >> 6, c = i & 63;
        float w0 = W[o * 128 + c];
        float w1 = W[o * 128 + 64 + c];
        W0t[c][o]  = w0;
        W21t[c][o] = w1 - w0;
    }
    int b  = blockIdx.x / (NN / 16);
    int nb = (blockIdx.x % (NN / 16)) * 16;
    #pragma unroll
    for (int it = 0; it < 4; ++it) {
        int i = it * 256 + t;
        int r = i >> 6, c = i & 63;
        xs[r][c] = xt[((size_t)(b * NN + nb + r)) * C + c];
    }
    __syncthreads();
    int o = t & 63, rg = t >> 6;
    #pragma unroll
    for (int rr = 0; rr < 4; ++rr) {
        int r = rg * 4 + rr;
        float z = 0.f, z2 = 0.f;
        #pragma unroll
        for (int c = 0; c < 64; ++c) {
            float xv = xs[r][c];
            z  = fmaf(xv, W0t[c][o],  z);
            z2 = fmaf(xv, W21t[c][o], z2);
        }
        size_t off = ((size_t)(b * NN + nb + r)) * 64 + o;
        Z[off]  = z;
        Z2[off] = z2;
    }
}

// ---------------- K3b: gather neighbors, per-(b,n,o) max/min over k, block-partial sums ----------------
// XCD swizzle: b = blockIdx&7 pins each batch's Z/Z2 (2MB) to one XCD's L2.
__global__ __launch_bounds__(256) void k3b_gather(const float* __restrict__ Z,
                                                  const float* __restrict__ Z2,
                                                  const int* __restrict__ idx,
                                                  float* __restrict__ maxY,
                                                  float* __restrict__ minY,
                                                  float* __restrict__ partials) {
    int t = threadIdx.x;
    int p = t >> 6, o = t & 63;
    int b = blockIdx.x & 7;
    int n = (blockIdx.x >> 3) * 4 + p;
    size_t base = (size_t)(b * NN + n);
    float z2 = Z2[base * 64 + o];
    __shared__ int sidx[4][KNN];
    if (o < KNN) sidx[p][o] = idx[base * KNN + o];
    __syncthreads();
    const float* Zb = Z + (size_t)b * NN * 64;
    float s1 = 0.f, s2 = 0.f, mx = -INFINITY, mn = INFINITY;
    #pragma unroll
    for (int k = 0; k < KNN; ++k) {
        float y = Zb[(size_t)sidx[p][k] * 64 + o] + z2;
        s1 += y;
        s2 = fmaf(y, y, s2);
        mx = fmaxf(mx, y);
        mn = fminf(mn, y);
    }
    maxY[base * 64 + o] = mx;
    minY[base * 64 + o] = mn;
    __shared__ float red[2][4][64];
    red[0][p][o] = s1;
    red[1][p][o] = s2;
    __syncthreads();
    if (t < 64) {
        float a = red[0][0][t] + red[0][1][t] + red[0][2][t] + red[0][3][t];
        float c = red[1][0][t] + red[1][1][t] + red[1][2][t] + red[1][3][t];
        partials[(size_t)blockIdx.x * 128 + t]      = a;
        partials[(size_t)blockIdx.x * 128 + 64 + t] = c;
    }
}

// ---------------- K4a: reduce 8192 partial rows -> 64 rows ----------------
__global__ __launch_bounds__(256) void k4a_reduce(const float* __restrict__ partials,
                                                  float* __restrict__ partials2) {
    int g = blockIdx.x;          // 0..63
    int t = threadIdx.x;
    int col = t & 127, half = t >> 7;
    float s = 0.f;
    for (int r = half; r < 128; r += 2)
        s += partials[((size_t)g * 128 + r) * 128 + col];
    __shared__ float red[2][128];
    red[half][col] = s;
    __syncthreads();
    if (t < 128) partials2[(size_t)g * 128 + t] = red[0][t] + red[1][t];
}

// ---------------- K4b: final stats -> scale/shift per channel ----------------
__global__ __launch_bounds__(128) void k4b_stats(const float* __restrict__ partials2,
                                                 const float* __restrict__ gamma,
                                                 const float* __restrict__ beta,
                                                 float* __restrict__ ss) {
    int t = threadIdx.x;   // 0..127
    double s = 0.0;
    for (int i = 0; i < 64; ++i)
        s += (double)partials2[(size_t)i * 128 + t];
    __shared__ double red[128];
    red[t] = s;
    __syncthreads();
    if (t < 64) {
        double a = red[t], c = red[64 + t];
        double M = (double)B * NN * KNN;
        double mean = a / M;
        double var  = c / M - mean * mean;
        float sc = gamma[t] * rsqrtf((float)var + 1e-5f);
        float sh = beta[t] - (float)mean * sc;
        ss[t]      = sc;
        ss[64 + t] = sh;
    }
}

// ---------------- K5: normalize + leakyrelu + transpose to (B,O,N) ----------------
__global__ __launch_bounds__(256) void k5_out(const float* __restrict__ maxY,
                                              const float* __restrict__ minY,
                                              const float* __restrict__ ss,
                                              float* __restrict__ out) {
    __shared__ float tile[64][65];
    __shared__ float sc[64], sh[64];
    int t = threadIdx.x;
    if (t < 64) { sc[t] = ss[t]; sh[t] = ss[64 + t]; }
    int b  = blockIdx.x / (NN / 64);
    int n0 = (blockIdx.x % (NN / 64)) * 64;
    __syncthreads();
    #pragma unroll
    for (int it = 0; it < 16; ++it) {
        int i = it * 256 + t;
        int nl = i >> 6, o = i & 63;
        size_t off = ((size_t)(b * NN + n0 + nl)) * 64 + o;
        float s = sc[o];
        float v = (s >= 0.f) ? maxY[off] : minY[off];
        v = fmaf(v, s, sh[o]);
        v = (v >= 0.f) ? v : 0.2f * v;
        tile[nl][o] = v;
    }
    __syncthreads();
    #pragma unroll
    for (int it = 0; it < 16; ++it) {
        int i = it * 256 + t;
        int o = i >> 6, nl = i & 63;
        out[((size_t)(b * O + o)) * NN + n0 + nl] = tile[nl][o];
    }
}

extern "C" void kernel_launch(void* const* d_in, const int* in_sizes, int n_in,
                              void* d_out, int out_size, void* d_ws, size_t ws_size,
                              hipStream_t stream) {
    const float* x     = (const float*)d_in[0];
    const float* W     = (const float*)d_in[1];
    const float* gamma = (const float*)d_in[2];
    const float* beta  = (const float*)d_in[3];
    float* out = (float*)d_out;

    float* ws = (float*)d_ws;
    float* xx = ws;                                                // B*N
    float* xt = xx + (size_t)B * NN;                               // B*N*C f32
    __hip_bfloat16* xh = (__hip_bfloat16*)(xt + (size_t)B * NN * C); // B*N*C bf16
    int*   idx = (int*)(xh + (size_t)B * NN * C);                  // B*N*KNN ints
    float* Z   = (float*)(idx + (size_t)B * NN * KNN);             // B*N*O
    float* Z2  = Z + (size_t)B * NN * O;
    float* maxY = Z2 + (size_t)B * NN * O;
    float* minY = maxY + (size_t)B * NN * O;
    float* partials  = minY + (size_t)B * NN * O;                  // (B*N/4)*128
    float* partials2 = partials + (size_t)(B * NN / 4) * 128;      // 64*128
    float* ss = partials2 + 64 * 128;                              // 128

    k1_split<<<B * (NN / 64), 256, 0, stream>>>(x, xt, xh, xx);
    k2_knn<<<B * (NN / 16), 256, 0, stream>>>(xh, xt, xx, idx);
    k3a_gemm<<<B * (NN / 16), 256, 0, stream>>>(xt, W, Z, Z2);
    k3b_gather<<<B * (NN / 4), 256, 0, stream>>>(Z, Z2, idx, maxY, minY, partials);
    k4a_reduce<<<64, 256, 0, stream>>>(partials, partials2);
    k4b_stats<<<1, 128, 0, stream>>>(partials2, gamma, beta, ss);
    k5_out<<<B * (NN / 64), 256, 0, stream>>>(maxY, minY, ss, out);
}

// Round 12
// 253.681 us; speedup vs baseline: 1.5128x; 1.0098x over previous
//
#include <hip/hip_runtime.h>
#include <hip/hip_bf16.h>
#include <math.h>

#define B 8
#define C 64
#define NN 4096
#define O 64
#define KNN 20

typedef float f32x4 __attribute__((ext_vector_type(4)));
typedef short short8_t __attribute__((ext_vector_type(8)));

__device__ inline uint32_t fkey(float f) {
    uint32_t u = __float_as_uint(f);
    return u ^ (((uint32_t)((int32_t)u >> 31)) | 0x80000000u);
}

__device__ inline uint32_t med3u(uint32_t a, uint32_t b, uint32_t c) {
    uint32_t r;
    asm("v_med3_u32 %0, %1, %2, %3" : "=v"(r) : "v"(a), "v"(b), "v"(c));
    return r;
}
__device__ inline uint32_t umax(uint32_t a, uint32_t b) { return a > b ? a : b; }
__device__ inline uint32_t umin(uint32_t a, uint32_t b) { return a < b ? a : b; }

// reduce over each 16-lane group, result in ALL 16 lanes. Pure VALU (DPP).
__device__ inline uint32_t maxall16(uint32_t v) {
    uint32_t t;
    t = (uint32_t)__builtin_amdgcn_update_dpp(0, (int)v, 0x140, 0xF, 0xF, true); // row_mirror
    v = umax(v, t);
    t = (uint32_t)__builtin_amdgcn_update_dpp(0, (int)v, 0x141, 0xF, 0xF, true); // row_half_mirror
    v = umax(v, t);
    t = (uint32_t)__builtin_amdgcn_update_dpp(0, (int)v, 0x4E, 0xF, 0xF, true);  // quad_perm [2,3,0,1]
    v = umax(v, t);
    t = (uint32_t)__builtin_amdgcn_update_dpp(0, (int)v, 0xB1, 0xF, 0xF, true);  // quad_perm [1,0,3,2]
    v = umax(v, t);
    return v;
}
__device__ inline uint32_t minall16(uint32_t v) {
    uint32_t t;
    t = (uint32_t)__builtin_amdgcn_update_dpp(0, (int)v, 0x140, 0xF, 0xF, true);
    v = umin(v, t);
    t = (uint32_t)__builtin_amdgcn_update_dpp(0, (int)v, 0x141, 0xF, 0xF, true);
    v = umin(v, t);
    t = (uint32_t)__builtin_amdgcn_update_dpp(0, (int)v, 0x4E, 0xF, 0xF, true);
    v = umin(v, t);
    t = (uint32_t)__builtin_amdgcn_update_dpp(0, (int)v, 0xB1, 0xF, 0xF, true);
    v = umin(v, t);
    return v;
}

// ---------------- K1: x (B,C,N) -> xt f32 (B,N,C) + xh bf16 (B,N,C), xx = sum_c x^2 ----------------
__global__ __launch_bounds__(256) void k1_split(const float* __restrict__ x,
                                                float* __restrict__ xt,
                                                __hip_bfloat16* __restrict__ xh,
                                                float* __restrict__ xx) {
    __shared__ float tile[64][65];
    int b  = blockIdx.x / (NN / 64);
    int n0 = (blockIdx.x % (NN / 64)) * 64;
    int t = threadIdx.x;
    #pragma unroll
    for (int it = 0; it < 16; ++it) {
        int i = it * 256 + t;
        int c = i >> 6, n = i & 63;
        tile[c][n] = x[(size_t)b * C * NN + (size_t)c * NN + n0 + n];
    }
    __syncthreads();
    #pragma unroll
    for (int it = 0; it < 16; ++it) {
        int i = it * 256 + t;
        int n = i >> 6, c = i & 63;
        float v = tile[c][n];
        size_t off = ((size_t)(b * NN + n0 + n)) * C + c;
        xt[off] = v;
        xh[off] = __float2bfloat16(v);
    }
    if (t < 64) {
        float s = 0.f;
        #pragma unroll
        for (int c = 0; c < 64; ++c) { float v = tile[c][t]; s = fmaf(v, v, s); }
        xx[(size_t)b * NN + t + n0] = s;
    }
}

// ---------------- K2: R11 structure + 2-deep sweep pipeline + depth-10 queues ----------------
// XCD swizzle: b = blockIdx&7 pins each batch's xh/xt/xx to one XCD's L2.
// Sweep: min-convention keys (d' = 2a - xxc - xxq - 2 < 0 -> raw as_uint orders
// inversely); per-lane depth-10 min-queues via med3 (R10-validated at pool 80).
// TWO tiles in flight (A/B register sets, hand-unrolled ×2, static indices):
// load t+2 issues before tile t's insert work -> ~240cy of independent work
// covers the ~200-250cy L2 latency that capped R8/R11 at VALUBusy ~50%.
// Per-wave top-20 DPP min-tournament -> mbuf; merge 80->32; exact f32 rerank of
// 32 (Round-1 arithmetic); rank-loop scatter. LDS padded (R10 lesson).
__global__ __launch_bounds__(256) void k2_knn(const __hip_bfloat16* __restrict__ xh,
                                              const float* __restrict__ xt,
                                              const float* __restrict__ xx,
                                              int* __restrict__ idx) {
    int b  = blockIdx.x & 7;
    int n0 = (blockIdx.x >> 3) << 4;
    int t = threadIdx.x;
    int w = t >> 6, lane = t & 63;
    int laneid = lane & 15, grp = lane >> 4;

    const __hip_bfloat16* xhb = xh + (size_t)b * NN * 64;
    const float* xxb = xx + (size_t)b * NN;
    const float* xtb = xt + (size_t)b * NN * 64;

    // A fragments: row = query n0+laneid, k = grp*8 .. grp*8+7 (and +32)
    size_t qoff = (size_t)(n0 + laneid) * 64 + grp * 8;
    short8_t Ah0 = *(const short8_t*)(xhb + qoff);
    short8_t Ah1 = *(const short8_t*)(xhb + qoff + 32);

    // per-query bias: -xxq - 2  (group's queries are n0+grp*4+j)
    float bq[4];
    #pragma unroll
    for (int j = 0; j < 4; ++j) bq[j] = -2.f - xxb[n0 + grp * 4 + j];

    // per-lane sorted min-queues (ascending), packed (key20|col12)
    uint32_t qq[4][10];
    #pragma unroll
    for (int j = 0; j < 4; ++j)
        #pragma unroll
        for (int i = 0; i < 10; ++i) qq[j][i] = 0xFFFFFFFFu;

    // ---- sweep: 64 tiles, 2-deep register double-buffer ----
    int cand0 = w * 1024 + laneid;
    {
        const __hip_bfloat16* bp = xhb + (size_t)cand0 * 64 + grp * 8;
        // tiles are 16 rows apart = 1024 bf16 elements
        short8_t A0 = *(const short8_t*)bp;
        short8_t A1 = *(const short8_t*)(bp + 32);
        float    Axx = xxb[cand0];
        short8_t Bb0 = *(const short8_t*)(bp + 1024);
        short8_t Bb1 = *(const short8_t*)(bp + 1024 + 32);
        float    Bxx = xxb[cand0 + 16];
        #pragma unroll 1
        for (int tt = 0; tt < 64; tt += 2) {
            // ---- tile tt (A regs); prefetch tt+2 into A ----
            {
                float xxc = Axx;
                f32x4 acc = {0.f, 0.f, 0.f, 0.f};
                acc = __builtin_amdgcn_mfma_f32_16x16x32_bf16(Ah0, A0, acc, 0, 0, 0);
                acc = __builtin_amdgcn_mfma_f32_16x16x32_bf16(Ah1, A1, acc, 0, 0, 0);
                // prefetch tile tt+2 (tail over-reads <=18KB into adjacent
                // workspace arrays — allocated, values unused)
                const __hip_bfloat16* np = bp + (size_t)(tt + 2) * 1024;
                A0 = *(const short8_t*)np;
                A1 = *(const short8_t*)(np + 32);
                Axx = xxb[cand0 + (tt + 2) * 16];
                int ci = cand0 + tt * 16;
                #pragma unroll
                for (int j = 0; j < 4; ++j) {
                    uint32_t u = __float_as_uint(fmaf(acc[j], 2.f, bq[j] - xxc));
                    uint32_t nv = (u & 0xFFFFF000u) | (uint32_t)ci;
                    #pragma unroll
                    for (int i = 9; i >= 1; --i)
                        qq[j][i] = med3u(qq[j][i - 1], qq[j][i], nv);
                    qq[j][0] = umin(qq[j][0], nv);
                }
            }
            // ---- tile tt+1 (B regs); prefetch tt+3 into B ----
            {
                float xxc = Bxx;
                f32x4 acc = {0.f, 0.f, 0.f, 0.f};
                acc = __builtin_amdgcn_mfma_f32_16x16x32_bf16(Ah0, Bb0, acc, 0, 0, 0);
                acc = __builtin_amdgcn_mfma_f32_16x16x32_bf16(Ah1, Bb1, acc, 0, 0, 0);
                const __hip_bfloat16* np = bp + (size_t)(tt + 3) * 1024;
                Bb0 = *(const short8_t*)np;
                Bb1 = *(const short8_t*)(np + 32);
                Bxx = xxb[cand0 + (tt + 3) * 16];
                int ci = cand0 + (tt + 1) * 16;
                #pragma unroll
                for (int j = 0; j < 4; ++j) {
                    uint32_t u = __float_as_uint(fmaf(acc[j], 2.f, bq[j] - xxc));
                    uint32_t nv = (u & 0xFFFFF000u) | (uint32_t)ci;
                    #pragma unroll
                    for (int i = 9; i >= 1; --i)
                        qq[j][i] = med3u(qq[j][i - 1], qq[j][i], nv);
                    qq[j][0] = umin(qq[j][0], nv);
                }
            }
        }
    }

    __shared__ uint32_t mbuf[16][4][20];   // [query][wave][slot] = packed
    __shared__ uint32_t cand[16][33];      // approx top-32 cols per query (padded)
    __shared__ uint32_t rkk[16][33];       // exact f32 keys (padded)
    __shared__ float qrow[16][68];         // f32 query rows (padded)

    // stage f32 query rows (loads overlap extraction)
    #pragma unroll
    for (int i = 0; i < 4; ++i) {
        int e = i * 256 + t;
        int r = e >> 6, cc = e & 63;
        qrow[r][cc] = xtb[(size_t)(n0 + r) * 64 + cc];
    }

    // ---- per-wave top-20 extraction: DPP min-tournament over 16 queue heads ----
    #pragma unroll 1
    for (int r = 0; r < 20; ++r) {
        #pragma unroll
        for (int j = 0; j < 4; ++j) {
            uint32_t bk = minall16(qq[j][0]);
            bool win = (qq[j][0] == bk);   // packed values unique -> single winner
            #pragma unroll
            for (int i = 0; i < 9; ++i) qq[j][i] = win ? qq[j][i + 1] : qq[j][i];
            qq[j][9] = win ? 0xFFFFFFFFu : qq[j][9];
            if (laneid == 0) mbuf[grp * 4 + j][w][r] = bk;
        }
    }
    __syncthreads();

    // ---- merge 80 -> approx top-32 per query (min-convention) ----
    {
        int q = w * 4 + grp;
        const uint32_t* mb = &mbuf[q][0][0];
        uint32_t e0 = mb[laneid],      e1 = mb[16 + laneid], e2 = mb[32 + laneid],
                 e3 = mb[48 + laneid], e4 = mb[64 + laneid];
        #pragma unroll 1
        for (int r = 0; r < 32; ++r) {
            uint32_t bk = umin(umin(umin(e0, e1), umin(e2, e3)), e4);
            bk = minall16(bk);
            e0 = (e0 == bk) ? 0xFFFFFFFFu : e0;
            e1 = (e1 == bk) ? 0xFFFFFFFFu : e1;
            e2 = (e2 == bk) ? 0xFFFFFFFFu : e2;
            e3 = (e3 == bk) ? 0xFFFFFFFFu : e3;
            e4 = (e4 == bk) ? 0xFFFFFFFFu : e4;
            if (laneid == 0) cand[q][r] = bk & 4095u;
        }
    }
    __syncthreads();

    // ---- exact f32 rerank of 32 candidates per query (Round-1 arithmetic) ----
    int rq = t >> 4, rs = t & 15;
    float qxx = xxb[n0 + rq];
    const float4* qr = (const float4*)qrow[rq];
    uint32_t mycol[2], mykey[2];
    #pragma unroll
    for (int e = 0; e < 2; ++e) {
        uint32_t col = cand[rq][rs + 16 * e];
        const float4* cr = (const float4*)(xtb + (size_t)col * 64);
        float a = 0.f;
        #pragma unroll
        for (int i = 0; i < 16; ++i) {
            float4 qv = qr[i], cv = cr[i];
            a = fmaf(qv.x, cv.x, a); a = fmaf(qv.y, cv.y, a);
            a = fmaf(qv.z, cv.z, a); a = fmaf(qv.w, cv.w, a);
        }
        float d = 2.f * a - qxx - xxb[col];
        mycol[e] = col;
        mykey[e] = fkey(d);
        rkk[rq][rs + 16 * e] = mykey[e];
    }
    __syncthreads();
    size_t ob = ((size_t)(b * NN) + n0 + rq) * KNN;
    #pragma unroll
    for (int e = 0; e < 2; ++e) {
        uint32_t ke = mykey[e], ce = mycol[e];
        int rank = 0;
        #pragma unroll
        for (int jj = 0; jj < 32; ++jj) {
            uint32_t kj = rkk[rq][jj], cj = cand[rq][jj];
            rank += (kj > ke || (kj == ke && cj < ce)) ? 1 : 0;
        }
        if (rank < KNN) idx[ob + rank] = (int)ce;
    }
}

// ---------------- K3a: Z = xt @ W0^T, Z2 = xt @ (W1-W0)^T ----------------
__global__ __launch_bounds__(256) void k3a_gemm(const float* __restrict__ xt,
                                                const float* __restrict__ W,
                                                float* __restrict__ Z,
                                                float* __restrict__ Z2) {
    __shared__ float W0t[64][65];
    __shared__ float W21t[64][65];
    __shared__ float xs[16][64];
    int t = threadIdx.x;
    #pragma unroll
    for (int it = 0; it < 16; ++it) {
        int i = it * 256 + t;
        int o = i >> 6, c = i & 63;
        float w0 = W[o * 128 + c];
        float w1 = W[o * 128 + 64 + c];
        W0t[c][o]  = w0;
        W21t[c][o] = w1 - w0;
    }
    int b  = blockIdx.x / (NN / 16);
    int nb = (blockIdx.x % (NN / 16)) * 16;
    #pragma unroll
    for (int it = 0; it < 4; ++it) {
        int i = it * 256 + t;
        int r = i >> 6, c = i & 63;
        xs[r][c] = xt[((size_t)(b * NN + nb + r)) * C + c];
    }
    __syncthreads();
    int o = t & 63, rg = t >> 6;
    #pragma unroll
    for (int rr = 0; rr < 4; ++rr) {
        int r = rg * 4 + rr;
        float z = 0.f, z2 = 0.f;
        #pragma unroll
        for (int c = 0; c < 64; ++c) {
            float xv = xs[r][c];
            z  = fmaf(xv, W0t[c][o],  z);
            z2 = fmaf(xv, W21t[c][o], z2);
        }
        size_t off = ((size_t)(b * NN + nb + r)) * 64 + o;
        Z[off]  = z;
        Z2[off] = z2;
    }
}

// ---------------- K3b: gather neighbors, per-(b,n,o) max/min over k, block-partial sums ----------------
// XCD swizzle: b = blockIdx&7 pins each batch's Z/Z2 (2MB) to one XCD's L2.
__global__ __launch_bounds__(256) void k3b_gather(const float* __restrict__ Z,
                                                  const float* __restrict__ Z2,
                                                  const int* __restrict__ idx,
                                                  float* __restrict__ maxY,
                                                  float* __restrict__ minY,
                                                  float* __restrict__ partials) {
    int t = threadIdx.x;
    int p = t >> 6, o = t & 63;
    int b = blockIdx.x & 7;
    int n = (blockIdx.x >> 3) * 4 + p;
    size_t base = (size_t)(b * NN + n);
    float z2 = Z2[base * 64 + o];
    __shared__ int sidx[4][KNN];
    if (o < KNN) sidx[p][o] = idx[base * KNN + o];
    __syncthreads();
    const float* Zb = Z + (size_t)b * NN * 64;
    float s1 = 0.f, s2 = 0.f, mx = -INFINITY, mn = INFINITY;
    #pragma unroll
    for (int k = 0; k < KNN; ++k) {
        float y = Zb[(size_t)sidx[p][k] * 64 + o] + z2;
        s1 += y;
        s2 = fmaf(y, y, s2);
        mx = fmaxf(mx, y);
        mn = fminf(mn, y);
    }
    maxY[base * 64 + o] = mx;
    minY[base * 64 + o] = mn;
    __shared__ float red[2][4][64];
    red[0][p][o] = s1;
    red[1][p][o] = s2;
    __syncthreads();
    if (t < 64) {
        float a = red[0][0][t] + red[0][1][t] + red[0][2][t] + red[0][3][t];
        float c = red[1][0][t] + red[1][1][t] + red[1][2][t] + red[1][3][t];
        partials[(size_t)blockIdx.x * 128 + t]      = a;
        partials[(size_t)blockIdx.x * 128 + 64 + t] = c;
    }
}

// ---------------- K4a: reduce 8192 partial rows -> 64 rows ----------------
__global__ __launch_bounds__(256) void k4a_reduce(const float* __restrict__ partials,
                                                  float* __restrict__ partials2) {
    int g = blockIdx.x;          // 0..63
    int t = threadIdx.x;
    int col = t & 127, half = t >> 7;
    float s = 0.f;
    for (int r = half; r < 128; r += 2)
        s += partials[((size_t)g * 128 + r) * 128 + col];
    __shared__ float red[2][128];
    red[half][col] = s;
    __syncthreads();
    if (t < 128) partials2[(size_t)g * 128 + t] = red[0][t] + red[1][t];
}

// ---------------- K4b: final stats -> scale/shift per channel ----------------
__global__ __launch_bounds__(128) void k4b_stats(const float* __restrict__ partials2,
                                                 const float* __restrict__ gamma,
                                                 const float* __restrict__ beta,
                                                 float* __restrict__ ss) {
    int t = threadIdx.x;   // 0..127
    double s = 0.0;
    for (int i = 0; i < 64; ++i)
        s += (double)partials2[(size_t)i * 128 + t];
    __shared__ double red[128];
    red[t] = s;
    __syncthreads();
    if (t < 64) {
        double a = red[t], c = red[64 + t];
        double M = (double)B * NN * KNN;
        double mean = a / M;
        double var  = c / M - mean * mean;
        float sc = gamma[t] * rsqrtf((float)var + 1e-5f);
        float sh = beta[t] - (float)mean * sc;
        ss[t]      = sc;
        ss[64 + t] = sh;
    }
}

// ---------------- K5: normalize + leakyrelu + transpose to (B,O,N) ----------------
__global__ __launch_bounds__(256) void k5_out(const float* __restrict__ maxY,
                                              const float* __restrict__ minY,
                                              const float* __restrict__ ss,
                                              float* __restrict__ out) {
    __shared__ float tile[64][65];
    __shared__ float sc[64], sh[64];
    int t = threadIdx.x;
    if (t < 64) { sc[t] = ss[t]; sh[t] = ss[64 + t]; }
    int b  = blockIdx.x / (NN / 64);
    int n0 = (blockIdx.x % (NN / 64)) * 64;
    __syncthreads();
    #pragma unroll
    for (int it = 0; it < 16; ++it) {
        int i = it * 256 + t;
        int nl = i >> 6, o = i & 63;
        size_t off = ((size_t)(b * NN + n0 + nl)) * 64 + o;
        float s = sc[o];
        float v = (s >= 0.f) ? maxY[off] : minY[off];
        v = fmaf(v, s, sh[o]);
        v = (v >= 0.f) ? v : 0.2f * v;
        tile[nl][o] = v;
    }
    __syncthreads();
    #pragma unroll
    for (int it = 0; it < 16; ++it) {
        int i = it * 256 + t;
        int o = i >> 6, nl = i & 63;
        out[((size_t)(b * O + o)) * NN + n0 + nl] = tile[nl][o];
    }
}

extern "C" void kernel_launch(void* const* d_in, const int* in_sizes, int n_in,
                              void* d_out, int out_size, void* d_ws, size_t ws_size,
                              hipStream_t stream) {
    const float* x     = (const float*)d_in[0];
    const float* W     = (const float*)d_in[1];
    const float* gamma = (const float*)d_in[2];
    const float* beta  = (const float*)d_in[3];
    float* out = (float*)d_out;

    float* ws = (float*)d_ws;
    float* xx = ws;                                                // B*N
    float* xt = xx + (size_t)B * NN;                               // B*N*C f32
    __hip_bfloat16* xh = (__hip_bfloat16*)(xt + (size_t)B * NN * C); // B*N*C bf16
    int*   idx = (int*)(xh + (size_t)B * NN * C);                  // B*N*KNN ints
    float* Z   = (float*)(idx + (size_t)B * NN * KNN);             // B*N*O
    float* Z2  = Z + (size_t)B * NN * O;
    float* maxY = Z2 + (size_t)B * NN * O;
    float* minY = maxY + (size_t)B * NN * O;
    float* partials  = minY + (size_t)B * NN * O;                  // (B*N/4)*128
    float* partials2 = partials + (size_t)(B * NN / 4) * 128;      // 64*128
    float* ss = partials2 + 64 * 128;                              // 128

    k1_split<<<B * (NN / 64), 256, 0, stream>>>(x, xt, xh, xx);
    k2_knn<<<B * (NN / 16), 256, 0, stream>>>(xh, xt, xx, idx);
    k3a_gemm<<<B * (NN / 16), 256, 0, stream>>>(xt, W, Z, Z2);
    k3b_gather<<<B * (NN / 4), 256, 0, stream>>>(Z, Z2, idx, maxY, minY, partials);
    k4a_reduce<<<64, 256, 0, stream>>>(partials, partials2);
    k4b_stats<<<1, 128, 0, stream>>>(partials2, gamma, beta, ss);
    k5_out<<<B * (NN / 64), 256, 0, stream>>>(maxY, minY, ss, out);
}